// Round 2
// baseline (816.993 us; speedup 1.0000x reference)
//
#include <hip/hip_runtime.h>
#include <math.h>

#define IC 64
#define OC 128
#define OHW 62
#define LOCS (OHW*OHW)          /* 3844 */
#define BATCH 32
#define Y_SIZE (BATCH*OC*LOCS)  /* 15740928 */
#define UPD_SIZE (OC*IC*9)      /* 73728 */
#define WNS 12                  /* padded taps per (k,c), 16B-aligned float4 rows */

// ---------------- K1: weight norm, layout wN[k][c][12] (taps 9..11 = 0) ----
__global__ void wnorm_kernel(const float* __restrict__ w, float* __restrict__ wN) {
    int k = blockIdx.x;      // 0..127
    int c = threadIdx.x;     // 0..63
    const float* wp = w + ((size_t)k*IC + c)*9;
    float v[9]; float s = 0.f;
#pragma unroll
    for (int t = 0; t < 9; ++t) { v[t] = wp[t]; s += v[t]*v[t]; }
#pragma unroll
    for (int off = 32; off > 0; off >>= 1) s += __shfl_xor(s, off);
    float nrm = sqrtf(s);
    if (nrm == 0.f) nrm = 1.f;
    float inv = 1.f / nrm;
    float* o = wN + ((size_t)k*IC + c)*WNS;
#pragma unroll
    for (int t = 0; t < 9; ++t) o[t] = v[t]*inv;
    o[9] = 0.f; o[10] = 0.f; o[11] = 0.f;
}

// ---------------- K2: conv + bias (no LDS; x rows via wave-uniform scalar loads)
// grid (62 oh, 32 b), 256 thr = 4 waves: wave = (khalf, owhalf); lane = k.
__global__ __launch_bounds__(256) void conv_kernel(
    const float* __restrict__ x, const float* __restrict__ wN,
    const float* __restrict__ bias, float* __restrict__ y)
{
    const int oh  = blockIdx.x;
    const int b   = blockIdx.y;
    const int wid = __builtin_amdgcn_readfirstlane((int)(threadIdx.x >> 6)); // 0..3 uniform
    const int lane = threadIdx.x & 63;
    const int khalf  = wid & 1;
    const int owhalf = wid >> 1;
    const int k   = khalf*64 + lane;
    const int ow0 = owhalf*32;

    float acc[32];
#pragma unroll
    for (int m = 0; m < 32; ++m) acc[m] = 0.f;

    const float* wk = wN + (size_t)k*IC*WNS;

#pragma unroll 2
    for (int c = 0; c < IC; ++c) {
        // per-lane weights for (k, c): 9 taps (3 aligned float4 loads, 12th..pad unused)
        float4 w0 = *(const float4*)(wk + c*WNS + 0);
        float4 w1 = *(const float4*)(wk + c*WNS + 4);
        float4 w2 = *(const float4*)(wk + c*WNS + 8);
        float wv[9] = {w0.x,w0.y,w0.z,w0.w, w1.x,w1.y,w1.z,w1.w, w2.x};

        const float* xc = x + (((size_t)b*IC + c)*64 + oh)*64 + ow0; // wave-uniform
#pragma unroll
        for (int i = 0; i < 3; ++i) {
            const float* xrow = xc + i*64;
            float xr[34];
#pragma unroll
            for (int t = 0; t < 32; ++t) xr[t] = xrow[t];   // uniform -> s_load
            if (owhalf == 0) { xr[32] = xrow[32]; xr[33] = xrow[33]; }
            else             { xr[32] = 0.f;      xr[33] = 0.f; }
#pragma unroll
            for (int j = 0; j < 3; ++j) {
                float wj = wv[i*3 + j];
#pragma unroll
                for (int m = 0; m < 32; ++m)
                    acc[m] += wj * xr[j + m];
            }
        }
    }

    float bk = bias[k];
    float* yrow = y + (((size_t)b*OC + k)*OHW + oh)*OHW + ow0;
#pragma unroll
    for (int m = 0; m < 32; ++m)
        if (ow0 + m < OHW) yrow[m] = acc[m] + bk;
}

// ---------------- K3: winners = argmax_k y (first-max tie-break) ----------
__global__ __launch_bounds__(256) void argmax_kernel(const float* __restrict__ y,
                                                     int* __restrict__ winners)
{
    const int bid = blockIdx.x;           // 0..511
    const int b = bid >> 4, ohq = bid & 15;
    const int ohsub = threadIdx.x >> 6;
    const int lane  = threadIdx.x & 63;
    const int oh = ohq*4 + ohsub;
    if (oh >= OHW) return;
    const float* yb = y + (size_t)b*OC*LOCS + oh*OHW + lane;
    float vmax = -3.4e38f; int imax = 0;
#pragma unroll 8
    for (int k = 0; k < OC; ++k) {
        float v = yb[(size_t)k*LOCS];
        if (v > vmax) { vmax = v; imax = k; }
    }
    if (lane < OHW)
        winners[(size_t)b*LOCS + oh*OHW + lane] = imax;
}

// ---------------- K4: Hebbian partials (chunked locs + run compression) ---
// grid (c=64, g=G); block loops BPG batches; LDS accumulator hl[128][9].
__global__ __launch_bounds__(256) void hebb_kernel(const float* __restrict__ x,
                                                   const int* __restrict__ winners,
                                                   float* __restrict__ part,
                                                   int G, int BPG)
{
    __shared__ float hl[OC*9];     // 4608 B
    __shared__ float xch[4096];    // 16 KB, one channel image
    const int c = blockIdx.x, g = blockIdx.y;
    const int tid = threadIdx.x;

    for (int t = tid; t < OC*9; t += 256) hl[t] = 0.f;

    for (int bb = 0; bb < BPG; ++bb) {
        int b = g*BPG + bb;
        __syncthreads();   // xch not in use (also covers hl init on bb==0)
        const float4* src = (const float4*)(x + ((size_t)b*IC + c)*4096);
        for (int t = tid; t < 1024; t += 256) ((float4*)xch)[t] = src[t];
        __syncthreads();

        // contiguous chunk per thread: decorrelates winners across lanes
        int s = (LOCS *  tid)      >> 8;
        int e = (LOCS * (tid + 1)) >> 8;
        const int* wb = winners + (size_t)b*LOCS;
        int curk = -1;
        float r[9];
#pragma unroll
        for (int t = 0; t < 9; ++t) r[t] = 0.f;
        for (int loc = s; loc < e; ++loc) {
            int kk = wb[loc];
            if (kk != curk) {
                if (curk >= 0) {
#pragma unroll
                    for (int t = 0; t < 9; ++t) atomicAdd(&hl[curk*9 + t], r[t]);
                }
                curk = kk;
#pragma unroll
                for (int t = 0; t < 9; ++t) r[t] = 0.f;
            }
            int ohh = (unsigned)loc / OHW;
            int oww = loc - ohh*OHW;
            const float* xp = xch + ohh*64 + oww;
#pragma unroll
            for (int i = 0; i < 3; ++i)
#pragma unroll
                for (int j = 0; j < 3; ++j)
                    r[i*3 + j] += xp[i*64 + j];
        }
        if (curk >= 0) {
#pragma unroll
            for (int t = 0; t < 9; ++t) atomicAdd(&hl[curk*9 + t], r[t]);
        }
    }
    __syncthreads();
    float* dst = part + ((size_t)c*G + g)*(OC*9);
    for (int t = tid; t < OC*9; t += 256) dst[t] = hl[t];
}

// ---------------- K5: reduce partials + scale ----------------
__global__ void final_kernel(const float* __restrict__ part, float* __restrict__ upd, int G) {
    int idx = blockIdx.x*256 + threadIdx.x;
    if (idx >= UPD_SIZE) return;
    int k  = idx / 576;
    int r  = idx - k*576;
    int c  = r / 9;
    int ij = r - c*9;
    float s = 0.f;
    for (int g = 0; g < G; ++g) s += part[((size_t)c*G + g)*(OC*9) + k*9 + ij];
    upd[idx] = s / 123008.0f;
}

extern "C" void kernel_launch(void* const* d_in, const int* in_sizes, int n_in,
                              void* d_out, int out_size, void* d_ws, size_t ws_size,
                              hipStream_t stream) {
    const float* x    = (const float*)d_in[0];
    const float* w    = (const float*)d_in[1];
    const float* bias = (const float*)d_in[2];
    float* out = (float*)d_out;
    float* y   = out;
    float* upd = out + Y_SIZE;

    const size_t wn_bytes  = (size_t)OC*IC*WNS*4;        // 393216
    const size_t win_bytes = (size_t)BATCH*LOCS*4;       // 492032
    // pick hebb parallelism from available scratch
    int G = 4;
    if (ws_size >= wn_bytes + win_bytes + (size_t)IC*16*OC*9*4) G = 16;
    else if (ws_size >= wn_bytes + win_bytes + (size_t)IC*8*OC*9*4) G = 8;
    int BPG = BATCH / G;

    float* wN      = (float*)d_ws;
    int*   winners = (int*)((char*)d_ws + wn_bytes);
    float* part    = (float*)((char*)d_ws + wn_bytes + win_bytes);

    wnorm_kernel <<<OC, IC, 0, stream>>>(w, wN);
    conv_kernel  <<<dim3(OHW, BATCH), 256, 0, stream>>>(x, wN, bias, y);
    argmax_kernel<<<BATCH*16, 256, 0, stream>>>(y, winners);
    hebb_kernel  <<<dim3(IC, G), 256, 0, stream>>>(x, winners, part, G, BPG);
    final_kernel <<<(UPD_SIZE + 255)/256, 256, 0, stream>>>(part, upd, G);
}

// Round 3
// 344.254 us; speedup vs baseline: 2.3732x; 2.3732x over previous
//
#include <hip/hip_runtime.h>
#include <math.h>

typedef __attribute__((ext_vector_type(8))) short bf16x8;
typedef __attribute__((ext_vector_type(4))) float f32x4;

#define IC 64
#define OC 128
#define OHW 62
#define LOCS (OHW*OHW)          /* 3844 */
#define BATCH 32
#define Y_SIZE (BATCH*OC*LOCS)  /* 15740928 */
#define UPD_SIZE (OC*IC*9)      /* 73728 */

__device__ __forceinline__ unsigned short f2bf(float f) {
    unsigned u = __float_as_uint(f);
    unsigned r = (u + 0x7FFFu + ((u >> 16) & 1u)) >> 16;   // RNE
    return (unsigned short)r;
}
__device__ __forceinline__ float bf2f(unsigned short h) {
    return __uint_as_float(((unsigned)h) << 16);
}

// ---------------- K1: weight norm -> wH/wL [k][ij][c] bf16 hi/lo ----------
__global__ void wnorm_kernel(const float* __restrict__ w,
                             short* __restrict__ wH, short* __restrict__ wL) {
    int k = blockIdx.x;      // 0..127
    int c = threadIdx.x;     // 0..63
    const float* wp = w + ((size_t)k*IC + c)*9;
    float v[9]; float s = 0.f;
#pragma unroll
    for (int t = 0; t < 9; ++t) { v[t] = wp[t]; s += v[t]*v[t]; }
#pragma unroll
    for (int off = 32; off > 0; off >>= 1) s += __shfl_xor(s, off);
    float nrm = sqrtf(s);
    if (nrm == 0.f) nrm = 1.f;
    float inv = 1.f / nrm;
#pragma unroll
    for (int t = 0; t < 9; ++t) {
        float f = v[t]*inv;
        unsigned short h = f2bf(f);
        wH[(k*9 + t)*64 + c] = (short)h;
        wL[(k*9 + t)*64 + c] = (short)f2bf(f - bf2f(h));
    }
}

// ---------------- K2: conv via split-bf16 MFMA + bias + argmax ------------
// grid (62 oh, 32 b), 256 thr = 4 waves; wave wv -> k-range [32wv,32wv+32).
__global__ __launch_bounds__(256) void conv_kernel(
    const float* __restrict__ x, const short* __restrict__ wH,
    const short* __restrict__ wL, const float* __restrict__ bias,
    float* __restrict__ y, int* __restrict__ winners)
{
    __shared__ short xh[3*66*64];    // [i][w(66)][c], bf16 hi, XOR-swizzled
    __shared__ short xl[3*66*64];    // lo
    __shared__ float redv[4][64];
    __shared__ int   redi[4][64];
    __shared__ float biasL[OC];

    const int oh = blockIdx.x, b = blockIdx.y;
    const int tid = threadIdx.x;
    if (tid < OC) biasL[tid] = bias[tid];

    // stage x[b,:,oh..oh+2,:] -> bf16 hi/lo, transposed [i][w][c]
    for (int it = tid; it < 1536; it += 256) {
        int wq = it & 15, c2 = (it >> 4) & 31, i = it >> 9;
        int c = c2*2, w0 = wq*4;
        const float* p = x + (((size_t)(b*IC + c))*64 + (oh + i))*64 + w0;
        float4 a0 = *(const float4*)p;
        float4 a1 = *(const float4*)(p + 4096);
        float f0[4] = {a0.x,a0.y,a0.z,a0.w};
        float f1[4] = {a1.x,a1.y,a1.z,a1.w};
#pragma unroll
        for (int jj = 0; jj < 4; ++jj) {
            int w = w0 + jj;
            unsigned short h0 = f2bf(f0[jj]), h1 = f2bf(f1[jj]);
            unsigned short l0 = f2bf(f0[jj] - bf2f(h0));
            unsigned short l1 = f2bf(f1[jj] - bf2f(h1));
            int e = (i*66 + w)*64 + c;                 // even
            int widx = (e ^ ((w & 7) << 3)) >> 1;      // uint index, swizzled
            ((unsigned*)xh)[widx] = (unsigned)h0 | ((unsigned)h1 << 16);
            ((unsigned*)xl)[widx] = (unsigned)l0 | ((unsigned)l1 << 16);
        }
    }
    __syncthreads();

    const int lane = tid & 63, wv = tid >> 6;
    const int l15 = lane & 15, lg = lane >> 4;
    const int kbase = wv*32;

    f32x4 acc[2][4];
#pragma unroll
    for (int kf = 0; kf < 2; ++kf)
#pragma unroll
        for (int nf = 0; nf < 4; ++nf)
            acc[kf][nf] = (f32x4){0.f,0.f,0.f,0.f};

#pragma unroll
    for (int s = 0; s < 18; ++s) {
        const int ij = s >> 1, ch = s & 1;
        const int i = ij / 3, j = ij % 3;
        bf16x8 ah[2], al[2];
#pragma unroll
        for (int kf = 0; kf < 2; ++kf) {
            int k = kbase + kf*16 + l15;
            size_t off = ((size_t)(k*9 + ij))*64 + ch*32 + lg*8;
            ah[kf] = *(const bf16x8*)(wH + off);
            al[kf] = *(const bf16x8*)(wL + off);
        }
        bf16x8 bh[4], bl[4];
#pragma unroll
        for (int nf = 0; nf < 4; ++nf) {
            int n = nf*16 + l15;
            int w = n + j;
            int e = (i*66 + w)*64 + ch*32 + lg*8;
            int si = e ^ ((w & 7) << 3);
            bh[nf] = *(const bf16x8*)(xh + si);
            bl[nf] = *(const bf16x8*)(xl + si);
        }
#pragma unroll
        for (int kf = 0; kf < 2; ++kf)
#pragma unroll
            for (int nf = 0; nf < 4; ++nf) {
                acc[kf][nf] = __builtin_amdgcn_mfma_f32_16x16x32_bf16(ah[kf], bh[nf], acc[kf][nf], 0, 0, 0);
                acc[kf][nf] = __builtin_amdgcn_mfma_f32_16x16x32_bf16(al[kf], bh[nf], acc[kf][nf], 0, 0, 0);
                acc[kf][nf] = __builtin_amdgcn_mfma_f32_16x16x32_bf16(ah[kf], bl[nf], acc[kf][nf], 0, 0, 0);
            }
    }

    // store y + argmax (C/D: row=(lg)*4+r, col=l15  [m89])
#pragma unroll
    for (int nf = 0; nf < 4; ++nf) {
        int n = nf*16 + l15;
        float vm = -3.4e38f; int im = 0;
#pragma unroll
        for (int kf = 0; kf < 2; ++kf)
#pragma unroll
            for (int r = 0; r < 4; ++r) {
                int k = kbase + kf*16 + lg*4 + r;
                float v = acc[kf][nf][r] + biasL[k];
                if (n < OHW) y[(((size_t)b*OC + k)*OHW + oh)*OHW + n] = v;
                if (v > vm) { vm = v; im = k; }       // ascending k, strict >
            }
        {
            float ov = __shfl_xor(vm, 16); int oi = __shfl_xor(im, 16);
            if (ov > vm || (ov == vm && oi < im)) { vm = ov; im = oi; }
            ov = __shfl_xor(vm, 32); oi = __shfl_xor(im, 32);
            if (ov > vm || (ov == vm && oi < im)) { vm = ov; im = oi; }
        }
        if (lg == 0) { redv[wv][n] = vm; redi[wv][n] = im; }
    }
    __syncthreads();
    if (tid < OHW) {
        float bv = redv[0][tid]; int bi = redi[0][tid];
#pragma unroll
        for (int wvv = 1; wvv < 4; ++wvv) {
            float v = redv[wvv][tid]; int i2 = redi[wvv][tid];
            if (v > bv || (v == bv && i2 < bi)) { bv = v; bi = i2; }
        }
        winners[(size_t)b*LOCS + oh*OHW + tid] = bi;
    }
}

// ---------------- K3: Hebbian update as one-hot-mask MFMA GEMM ------------
// grid 256 = (b, ohtile of 8 rows); 512 thr = 8 waves; wave wv -> 16 k.
// For shift j: hebb[k][c][i][j] += sum_w mask_j(w)*x[c][r+i][w], mask built
// from winners (A-frag, in-register), x rows bf16 in LDS (B-frag, aligned).
__global__ __launch_bounds__(512) void hebb_kernel(
    const float* __restrict__ x, const int* __restrict__ winners,
    float* __restrict__ hacc)
{
    __shared__ short xR[IC*10*72];   // [c][row][72], bf16 hi; 92160 B
    __shared__ int winL[8*64];       // winners rows, ow>=62 -> -1

    const int bid = blockIdx.x;
    const int b = bid >> 3, tile = bid & 7;
    const int oh0 = tile*8;
    const int NR = (tile == 7) ? 6 : 8;
    const int rows = NR + 2;
    const int tid = threadIdx.x;

    for (int it = tid; it < IC*rows*16; it += 512) {
        int wq = it & 15;
        int t2 = it >> 4;
        int r = t2 % rows, c = t2 / rows;
        const float* p = x + (((size_t)(b*IC + c))*64 + (oh0 + r))*64 + wq*4;
        float4 a = *(const float4*)p;
        unsigned u0 = (unsigned)f2bf(a.x) | ((unsigned)f2bf(a.y) << 16);
        unsigned u1 = (unsigned)f2bf(a.z) | ((unsigned)f2bf(a.w) << 16);
        int e = (c*10 + r)*72 + wq*4;
        ((unsigned*)xR)[(e >> 1)]     = u0;
        ((unsigned*)xR)[(e >> 1) + 1] = u1;
    }
    for (int t = tid; t < NR*64; t += 512) {
        int r = t >> 6, ow = t & 63;
        winL[t] = (ow < OHW) ? winners[(size_t)b*LOCS + (oh0 + r)*OHW + ow] : -1;
    }
    __syncthreads();

    const int lane = tid & 63, wv = tid >> 6;
    const int l15 = lane & 15, lg = lane >> 4;
    const int myk = wv*16 + l15;

    int off0[12];
#pragma unroll
    for (int nf = 0; nf < 12; ++nf) {
        int np = nf*16 + l15;        // 0..191 = c*3+i
        int c = np / 3, i = np % 3;
        off0[nf] = (c*10 + i)*72;
    }

    f32x4 acc[3][12];
#pragma unroll
    for (int j = 0; j < 3; ++j)
#pragma unroll
        for (int nf = 0; nf < 12; ++nf)
            acc[j][nf] = (f32x4){0.f,0.f,0.f,0.f};

    for (int r = 0; r < NR; ++r) {
#pragma unroll
        for (int h = 0; h < 2; ++h) {
            const int base = h*32 + lg*8;
            const int* wrow = &winL[r*64];
            int wreg[8];
            *(int4*)&wreg[0] = *(const int4*)&wrow[base];
            *(int4*)&wreg[4] = *(const int4*)&wrow[base + 4];
            const int wm1 = (base >= 1) ? wrow[base-1] : -1;
            const int wm2 = (base >= 2) ? wrow[base-2] : -1;
            union U8 { unsigned u[4]; bf16x8 v; };
            bf16x8 am[3];
#pragma unroll
            for (int j = 0; j < 3; ++j) {
                U8 tmp;
#pragma unroll
                for (int p2 = 0; p2 < 4; ++p2) {
                    int t0 = p2*2, t1 = t0 + 1;
                    int s0 = (t0 >= j) ? wreg[t0-j] : ((j - t0 == 1) ? wm1 : wm2);
                    int s1 = (t1 >= j) ? wreg[t1-j] : ((j - t1 == 1) ? wm1 : wm2);
                    tmp.u[p2] = ((s0 == myk) ? 0x3F80u : 0u)
                              | (((s1 == myk) ? 0x3F80u : 0u) << 16);
                }
                am[j] = tmp.v;
            }
#pragma unroll
            for (int nf = 0; nf < 12; ++nf) {
                const bf16x8 bb = *(const bf16x8*)&xR[off0[nf] + r*72 + base];
#pragma unroll
                for (int j = 0; j < 3; ++j)
                    acc[j][nf] = __builtin_amdgcn_mfma_f32_16x16x32_bf16(am[j], bb, acc[j][nf], 0, 0, 0);
            }
        }
    }

#pragma unroll
    for (int j = 0; j < 3; ++j)
#pragma unroll
        for (int nf = 0; nf < 12; ++nf) {
            int np = nf*16 + l15;
            int c = np / 3, i = np % 3;
#pragma unroll
            for (int r4 = 0; r4 < 4; ++r4) {
                int k = wv*16 + lg*4 + r4;
                atomicAdd(&hacc[(size_t)k*576 + c*9 + i*3 + j], acc[j][nf][r4]);
            }
        }
}

// ---------------- K4: scale ----------------
__global__ void final_kernel(const float* __restrict__ hacc, float* __restrict__ upd) {
    int idx = blockIdx.x*256 + threadIdx.x;
    if (idx < UPD_SIZE) upd[idx] = hacc[idx] / 123008.0f;
}

extern "C" void kernel_launch(void* const* d_in, const int* in_sizes, int n_in,
                              void* d_out, int out_size, void* d_ws, size_t ws_size,
                              hipStream_t stream) {
    const float* x    = (const float*)d_in[0];
    const float* w    = (const float*)d_in[1];
    const float* bias = (const float*)d_in[2];
    float* out = (float*)d_out;
    float* y   = out;
    float* upd = out + Y_SIZE;

    // ws: wH 147456 | wL 147456 | winners 492032 | hacc 294912  (~1.08 MB)
    short* wHs     = (short*)d_ws;
    short* wLs     = (short*)((char*)d_ws + 147456);
    int*   winners = (int*)((char*)d_ws + 294912);
    float* hacc    = (float*)((char*)d_ws + 294912 + 492032);

    hipMemsetAsync(hacc, 0, (size_t)UPD_SIZE*4, stream);
    wnorm_kernel<<<OC, IC, 0, stream>>>(w, wHs, wLs);
    conv_kernel<<<dim3(OHW, BATCH), 256, 0, stream>>>(x, wHs, wLs, bias, y, winners);
    hebb_kernel<<<BATCH*8, 512, 0, stream>>>(x, winners, hacc);
    final_kernel<<<(UPD_SIZE + 255)/256, 256, 0, stream>>>(hacc, upd);
}

// Round 4
// 205.516 us; speedup vs baseline: 3.9753x; 1.6751x over previous
//
#include <hip/hip_runtime.h>
#include <math.h>

typedef __attribute__((ext_vector_type(8))) short bf16x8;
typedef __attribute__((ext_vector_type(4))) float f32x4;

#define IC 64
#define OC 128
#define OHW 62
#define LOCS (OHW*OHW)          /* 3844 */
#define BATCH 32
#define Y_SIZE (BATCH*OC*LOCS)  /* 15740928 */
#define UPD_SIZE (OC*IC*9)      /* 73728 */

__device__ __forceinline__ unsigned short f2bf(float f) {
    unsigned u = __float_as_uint(f);
    unsigned r = (u + 0x7FFFu + ((u >> 16) & 1u)) >> 16;   // RNE
    return (unsigned short)r;
}
__device__ __forceinline__ float bf2f(unsigned short h) {
    return __uint_as_float(((unsigned)h) << 16);
}

// ---------------- K1: weight norm -> wH/wL [k][ij][c] bf16 hi/lo ----------
__global__ void wnorm_kernel(const float* __restrict__ w,
                             short* __restrict__ wH, short* __restrict__ wL) {
    int k = blockIdx.x;      // 0..127
    int c = threadIdx.x;     // 0..63
    const float* wp = w + ((size_t)k*IC + c)*9;
    float v[9]; float s = 0.f;
#pragma unroll
    for (int t = 0; t < 9; ++t) { v[t] = wp[t]; s += v[t]*v[t]; }
#pragma unroll
    for (int off = 32; off > 0; off >>= 1) s += __shfl_xor(s, off);
    float nrm = sqrtf(s);
    if (nrm == 0.f) nrm = 1.f;
    float inv = 1.f / nrm;
#pragma unroll
    for (int t = 0; t < 9; ++t) {
        float f = v[t]*inv;
        unsigned short h = f2bf(f);
        wH[(k*9 + t)*64 + c] = (short)h;
        wL[(k*9 + t)*64 + c] = (short)f2bf(f - bf2f(h));
    }
}

// ---------------- K2: conv via split-bf16 MFMA + bias + argmax ------------
// grid (62 oh, 32 b), 256 thr = 4 waves; wave wv -> k-range [32wv,32wv+32).
__global__ __launch_bounds__(256) void conv_kernel(
    const float* __restrict__ x, const short* __restrict__ wH,
    const short* __restrict__ wL, const float* __restrict__ bias,
    float* __restrict__ y, int* __restrict__ winners)
{
    __shared__ short xh[3*66*64];    // [i][w(66)][c], bf16 hi, XOR-swizzled
    __shared__ short xl[3*66*64];    // lo
    __shared__ float redv[4][64];
    __shared__ int   redi[4][64];
    __shared__ float biasL[OC];

    const int oh = blockIdx.x, b = blockIdx.y;
    const int tid = threadIdx.x;
    if (tid < OC) biasL[tid] = bias[tid];

    // stage x[b,:,oh..oh+2,:] -> bf16 hi/lo, transposed [i][w][c]
    for (int it = tid; it < 1536; it += 256) {
        int wq = it & 15, c2 = (it >> 4) & 31, i = it >> 9;
        int c = c2*2, w0 = wq*4;
        const float* p = x + (((size_t)(b*IC + c))*64 + (oh + i))*64 + w0;
        float4 a0 = *(const float4*)p;
        float4 a1 = *(const float4*)(p + 4096);
        float f0[4] = {a0.x,a0.y,a0.z,a0.w};
        float f1[4] = {a1.x,a1.y,a1.z,a1.w};
#pragma unroll
        for (int jj = 0; jj < 4; ++jj) {
            int w = w0 + jj;
            unsigned short h0 = f2bf(f0[jj]), h1 = f2bf(f1[jj]);
            unsigned short l0 = f2bf(f0[jj] - bf2f(h0));
            unsigned short l1 = f2bf(f1[jj] - bf2f(h1));
            int e = (i*66 + w)*64 + c;                 // even
            int widx = (e ^ ((w & 7) << 3)) >> 1;      // uint index, swizzled
            ((unsigned*)xh)[widx] = (unsigned)h0 | ((unsigned)h1 << 16);
            ((unsigned*)xl)[widx] = (unsigned)l0 | ((unsigned)l1 << 16);
        }
    }
    __syncthreads();

    const int lane = tid & 63, wv = tid >> 6;
    const int l15 = lane & 15, lg = lane >> 4;
    const int kbase = wv*32;

    f32x4 acc[2][4];
#pragma unroll
    for (int kf = 0; kf < 2; ++kf)
#pragma unroll
        for (int nf = 0; nf < 4; ++nf)
            acc[kf][nf] = (f32x4){0.f,0.f,0.f,0.f};

#pragma unroll
    for (int s = 0; s < 18; ++s) {
        const int ij = s >> 1, ch = s & 1;
        const int i = ij / 3, j = ij % 3;
        bf16x8 ah[2], al[2];
#pragma unroll
        for (int kf = 0; kf < 2; ++kf) {
            int k = kbase + kf*16 + l15;
            size_t off = ((size_t)(k*9 + ij))*64 + ch*32 + lg*8;
            ah[kf] = *(const bf16x8*)(wH + off);
            al[kf] = *(const bf16x8*)(wL + off);
        }
        bf16x8 bh[4], bl[4];
#pragma unroll
        for (int nf = 0; nf < 4; ++nf) {
            int n = nf*16 + l15;
            int w = n + j;
            int e = (i*66 + w)*64 + ch*32 + lg*8;
            int si = e ^ ((w & 7) << 3);
            bh[nf] = *(const bf16x8*)(xh + si);
            bl[nf] = *(const bf16x8*)(xl + si);
        }
#pragma unroll
        for (int kf = 0; kf < 2; ++kf)
#pragma unroll
            for (int nf = 0; nf < 4; ++nf) {
                acc[kf][nf] = __builtin_amdgcn_mfma_f32_16x16x32_bf16(ah[kf], bh[nf], acc[kf][nf], 0, 0, 0);
                acc[kf][nf] = __builtin_amdgcn_mfma_f32_16x16x32_bf16(al[kf], bh[nf], acc[kf][nf], 0, 0, 0);
                acc[kf][nf] = __builtin_amdgcn_mfma_f32_16x16x32_bf16(ah[kf], bl[nf], acc[kf][nf], 0, 0, 0);
            }
    }

    // store y + argmax (C/D: row=(lg)*4+r, col=l15  [m89])
#pragma unroll
    for (int nf = 0; nf < 4; ++nf) {
        int n = nf*16 + l15;
        float vm = -3.4e38f; int im = 0;
#pragma unroll
        for (int kf = 0; kf < 2; ++kf)
#pragma unroll
            for (int r = 0; r < 4; ++r) {
                int k = kbase + kf*16 + lg*4 + r;
                float v = acc[kf][nf][r] + biasL[k];
                if (n < OHW) y[(((size_t)b*OC + k)*OHW + oh)*OHW + n] = v;
                if (v > vm) { vm = v; im = k; }       // ascending k, strict >
            }
        {
            float ov = __shfl_xor(vm, 16); int oi = __shfl_xor(im, 16);
            if (ov > vm || (ov == vm && oi < im)) { vm = ov; im = oi; }
            ov = __shfl_xor(vm, 32); oi = __shfl_xor(im, 32);
            if (ov > vm || (ov == vm && oi < im)) { vm = ov; im = oi; }
        }
        if (lg == 0) { redv[wv][n] = vm; redi[wv][n] = im; }
    }
    __syncthreads();
    if (tid < OHW) {
        float bv = redv[0][tid]; int bi = redi[0][tid];
#pragma unroll
        for (int wvv = 1; wvv < 4; ++wvv) {
            float v = redv[wvv][tid]; int i2 = redi[wvv][tid];
            if (v > bv || (v == bv && i2 < bi)) { bv = v; bi = i2; }
        }
        winners[(size_t)b*LOCS + oh*OHW + tid] = bi;
    }
}

// ---------------- K3: Hebbian via one-hot-mask MFMA, per-block partials ---
// grid nblk (<=256); block loops tiles t = bid, bid+nblk, ... accumulating in
// registers; ONE non-atomic partial write per block: part[bid][row][k],
// row = c*9+i*3+j (576), k-contiguous float4 from the C-frag.
__global__ __launch_bounds__(512) void hebb_kernel(
    const float* __restrict__ x, const int* __restrict__ winners,
    float* __restrict__ part, int nblk)
{
    __shared__ short xR[IC*10*72];   // [c][row][72], bf16 hi; 92160 B
    __shared__ int winL[8*64];       // winners rows, ow>=62 -> -1

    const int tid = threadIdx.x;
    const int lane = tid & 63, wv = tid >> 6;
    const int l15 = lane & 15, lg = lane >> 4;
    const int myk = wv*16 + l15;

    int off0[12];
#pragma unroll
    for (int nf = 0; nf < 12; ++nf) {
        int np = nf*16 + l15;        // 0..191 = c*3+i
        int c = np / 3, i = np % 3;
        off0[nf] = (c*10 + i)*72;
    }

    f32x4 acc[3][12];
#pragma unroll
    for (int j = 0; j < 3; ++j)
#pragma unroll
        for (int nf = 0; nf < 12; ++nf)
            acc[j][nf] = (f32x4){0.f,0.f,0.f,0.f};

    for (int t = blockIdx.x; t < 256; t += nblk) {
        const int b = t >> 3, tile = t & 7;
        const int oh0 = tile*8;
        const int NR = (tile == 7) ? 6 : 8;
        const int rows = NR + 2;

        __syncthreads();   // xR/winL free from previous tile
        for (int it = tid; it < IC*rows*16; it += 512) {
            int wq = it & 15;
            int t2 = it >> 4;
            int r = t2 % rows, c = t2 / rows;
            const float* p = x + (((size_t)(b*IC + c))*64 + (oh0 + r))*64 + wq*4;
            float4 a = *(const float4*)p;
            unsigned u0 = (unsigned)f2bf(a.x) | ((unsigned)f2bf(a.y) << 16);
            unsigned u1 = (unsigned)f2bf(a.z) | ((unsigned)f2bf(a.w) << 16);
            int e = (c*10 + r)*72 + wq*4;
            ((unsigned*)xR)[(e >> 1)]     = u0;
            ((unsigned*)xR)[(e >> 1) + 1] = u1;
        }
        for (int tt = tid; tt < NR*64; tt += 512) {
            int r = tt >> 6, ow = tt & 63;
            winL[tt] = (ow < OHW) ? winners[(size_t)b*LOCS + (oh0 + r)*OHW + ow] : -1;
        }
        __syncthreads();

        for (int r = 0; r < NR; ++r) {
#pragma unroll
            for (int h = 0; h < 2; ++h) {
                const int base = h*32 + lg*8;
                const int* wrow = &winL[r*64];
                int wreg[8];
                *(int4*)&wreg[0] = *(const int4*)&wrow[base];
                *(int4*)&wreg[4] = *(const int4*)&wrow[base + 4];
                const int wm1 = (base >= 1) ? wrow[base-1] : -1;
                const int wm2 = (base >= 2) ? wrow[base-2] : -1;
                union U8 { unsigned u[4]; bf16x8 v; };
                bf16x8 am[3];
#pragma unroll
                for (int j = 0; j < 3; ++j) {
                    U8 tmp;
#pragma unroll
                    for (int p2 = 0; p2 < 4; ++p2) {
                        int t0 = p2*2, t1 = t0 + 1;
                        int s0 = (t0 >= j) ? wreg[t0-j] : ((j - t0 == 1) ? wm1 : wm2);
                        int s1 = (t1 >= j) ? wreg[t1-j] : ((j - t1 == 1) ? wm1 : wm2);
                        tmp.u[p2] = ((s0 == myk) ? 0x3F80u : 0u)
                                  | (((s1 == myk) ? 0x3F80u : 0u) << 16);
                    }
                    am[j] = tmp.v;
                }
#pragma unroll
                for (int nf = 0; nf < 12; ++nf) {
                    const bf16x8 bb = *(const bf16x8*)&xR[off0[nf] + r*72 + base];
#pragma unroll
                    for (int j = 0; j < 3; ++j)
                        acc[j][nf] = __builtin_amdgcn_mfma_f32_16x16x32_bf16(am[j], bb, acc[j][nf], 0, 0, 0);
                }
            }
        }
    }

    // one partial write, no atomics: part[bid][row=np*3+j][k], float4 over k
    float* dst = part + (size_t)blockIdx.x*UPD_SIZE;
#pragma unroll
    for (int j = 0; j < 3; ++j)
#pragma unroll
        for (int nf = 0; nf < 12; ++nf) {
            int np = nf*16 + l15;
            int row = np*3 + j;                 // == c*9 + i*3 + j
            int k0  = wv*16 + lg*4;
            *(f32x4*)(dst + row*OC + k0) = acc[j][nf];
        }
}

// ---------------- K4: reduce partials (coalesced) + scale + transpose -----
__global__ __launch_bounds__(256) void final_kernel(const float* __restrict__ part,
                                                    float* __restrict__ upd, int nblk) {
    int t = blockIdx.x*256 + threadIdx.x;      // 18432 threads
    int idx = t*4;                              // element base in [row][k] plane
    f32x4 s = (f32x4){0.f,0.f,0.f,0.f};
    for (int p = 0; p < nblk; ++p)
        s += *(const f32x4*)(part + (size_t)p*UPD_SIZE + idx);
    int row = idx >> 7;        // /128
    int k0  = idx & 127;
    const float inv = 1.0f / 123008.0f;
#pragma unroll
    for (int r = 0; r < 4; ++r)
        upd[(size_t)(k0 + r)*576 + row] = s[r] * inv;
}

extern "C" void kernel_launch(void* const* d_in, const int* in_sizes, int n_in,
                              void* d_out, int out_size, void* d_ws, size_t ws_size,
                              hipStream_t stream) {
    const float* x    = (const float*)d_in[0];
    const float* w    = (const float*)d_in[1];
    const float* bias = (const float*)d_in[2];
    float* out = (float*)d_out;
    float* y   = out;
    float* upd = out + Y_SIZE;

    // ws: wH 147456 | wL 147456 | winners 492032 | partials nblk*294912
    const size_t fixed = 147456 + 147456 + 492032;   // 786944
    short* wHs     = (short*)d_ws;
    short* wLs     = (short*)((char*)d_ws + 147456);
    int*   winners = (int*)((char*)d_ws + 294912);
    float* part    = (float*)((char*)d_ws + fixed);

    size_t avail = (ws_size > fixed) ? (ws_size - fixed) : 0;
    int nblk = (int)(avail / ((size_t)UPD_SIZE*4));
    if (nblk > 256) nblk = 256;
    if (nblk < 1)   nblk = 1;   // ws_size >= 1.08MB held in prior rounds

    wnorm_kernel<<<OC, IC, 0, stream>>>(w, wHs, wLs);
    conv_kernel<<<dim3(OHW, BATCH), 256, 0, stream>>>(x, wHs, wLs, bias, y, winners);
    hebb_kernel<<<nblk, 512, 0, stream>>>(x, winners, part, nblk);
    final_kernel<<<UPD_SIZE/4/256, 256, 0, stream>>>(part, upd, nblk);
}

// Round 5
// 202.110 us; speedup vs baseline: 4.0423x; 1.0169x over previous
//
#include <hip/hip_runtime.h>
#include <math.h>

typedef __attribute__((ext_vector_type(8))) short bf16x8;
typedef __attribute__((ext_vector_type(4))) float f32x4;

#define IC 64
#define OC 128
#define OHW 62
#define LOCS (OHW*OHW)          /* 3844 */
#define BATCH 32
#define Y_SIZE (BATCH*OC*LOCS)  /* 15740928 */
#define UPD_SIZE (OC*IC*9)      /* 73728 */

#define SWZ(w) ((((w) ^ ((w) >> 3)) & 7) << 3)   /* short-granule XOR slot */

__device__ __forceinline__ unsigned short f2bf(float f) {
    unsigned u = __float_as_uint(f);
    unsigned r = (u + 0x7FFFu + ((u >> 16) & 1u)) >> 16;   // RNE
    return (unsigned short)r;
}
__device__ __forceinline__ float bf2f(unsigned short h) {
    return __uint_as_float(((unsigned)h) << 16);
}

// ---------------- K1: weight norm -> wH/wL [ij][ch][lg][k][8c] bf16 hi/lo --
__global__ void wnorm_kernel(const float* __restrict__ w,
                             short* __restrict__ wH, short* __restrict__ wL) {
    int k = blockIdx.x;      // 0..127
    int c = threadIdx.x;     // 0..63
    const float* wp = w + ((size_t)k*IC + c)*9;
    float v[9]; float s = 0.f;
#pragma unroll
    for (int t = 0; t < 9; ++t) { v[t] = wp[t]; s += v[t]*v[t]; }
#pragma unroll
    for (int off = 32; off > 0; off >>= 1) s += __shfl_xor(s, off);
    float nrm = sqrtf(s);
    if (nrm == 0.f) nrm = 1.f;
    float inv = 1.f / nrm;
    const int ch = c >> 5, lg = (c >> 3) & 3, pos = c & 7;
#pragma unroll
    for (int t = 0; t < 9; ++t) {
        float f = v[t]*inv;
        unsigned short h = f2bf(f);
        size_t off = ((size_t)((t*2 + ch)*4 + lg)*128 + k)*8 + pos;
        wH[off] = (short)h;
        wL[off] = (short)f2bf(f - bf2f(h));
    }
}

// ---------------- K2: conv via split-bf16 MFMA + bias + argmax ------------
// grid (31 ohtiles, 32 b), 256 thr = 4 waves; block -> rows oh0, oh0+1.
__global__ __launch_bounds__(256, 2) void conv_kernel(
    const float* __restrict__ x, const short* __restrict__ wH,
    const short* __restrict__ wL, const float* __restrict__ bias,
    float* __restrict__ y, int* __restrict__ winners)
{
    __shared__ short xh[4*66*64];    // [i(4)][w(66)][c(64)], bf16 hi, swizzled
    __shared__ short xl[4*66*64];
    __shared__ float redv[4][2][64];
    __shared__ int   redi[4][2][64];
    __shared__ float biasL[OC];

    const int oh0 = blockIdx.x*2, b = blockIdx.y;
    const int tid = threadIdx.x;
    if (tid < OC) biasL[tid] = bias[tid];

    // stage x[b,:,oh0..oh0+3,:] -> bf16 hi/lo, transposed [i][w][c], swizzled
    for (int it = tid; it < 2048; it += 256) {
        int wq = it & 15, c2 = (it >> 4) & 31, i = it >> 9;
        int c = c2*2, w0 = wq*4;
        const float* p = x + (((size_t)(b*IC + c))*64 + (oh0 + i))*64 + w0;
        float4 a0 = *(const float4*)p;
        float4 a1 = *(const float4*)(p + 4096);
        float f0[4] = {a0.x,a0.y,a0.z,a0.w};
        float f1[4] = {a1.x,a1.y,a1.z,a1.w};
#pragma unroll
        for (int jj = 0; jj < 4; ++jj) {
            int w = w0 + jj;
            unsigned short h0 = f2bf(f0[jj]), h1 = f2bf(f1[jj]);
            unsigned short l0 = f2bf(f0[jj] - bf2f(h0));
            unsigned short l1 = f2bf(f1[jj] - bf2f(h1));
            int e = (i*66 + w)*64 + c;
            int widx = (e ^ SWZ(w)) >> 1;              // uint index, swizzled
            ((unsigned*)xh)[widx] = (unsigned)h0 | ((unsigned)h1 << 16);
            ((unsigned*)xl)[widx] = (unsigned)l0 | ((unsigned)l1 << 16);
        }
    }
    {   // zero pad cols w=64,65 (read by nf=3 taps, outputs discarded)
        int i = tid >> 6, w = 64 + ((tid >> 5) & 1), c = (tid & 31)*2;
        int widx = (((i*66 + w)*64 + c) ^ SWZ(w)) >> 1;
        ((unsigned*)xh)[widx] = 0u;
        ((unsigned*)xl)[widx] = 0u;
    }
    __syncthreads();

    const int lane = tid & 63, wv = tid >> 6;
    const int l15 = lane & 15, lg = lane >> 4;
    const int kbase = wv*32;

    f32x4 acc[2][2][4];   // [rr][kf][nf]
#pragma unroll
    for (int rr = 0; rr < 2; ++rr)
#pragma unroll
        for (int kf = 0; kf < 2; ++kf)
#pragma unroll
            for (int nf = 0; nf < 4; ++nf)
                acc[rr][kf][nf] = (f32x4){0.f,0.f,0.f,0.f};

#pragma unroll
    for (int s = 0; s < 18; ++s) {
        const int ij = s >> 1, ch = s & 1;
        const int i = ij / 3, j = ij % 3;
        bf16x8 ah[2], al[2];
#pragma unroll
        for (int kf = 0; kf < 2; ++kf) {
            int k = kbase + kf*16 + l15;
            size_t off = ((size_t)((ij*2 + ch)*4 + lg)*128 + k)*8;
            ah[kf] = *(const bf16x8*)(wH + off);       // 16 lanes = 256B burst
            al[kf] = *(const bf16x8*)(wL + off);
        }
#pragma unroll
        for (int rr = 0; rr < 2; ++rr) {
            bf16x8 bh[4], bl[4];
#pragma unroll
            for (int nf = 0; nf < 4; ++nf) {
                int w = nf*16 + l15 + j;
                int e = ((rr + i)*66 + w)*64 + ch*32 + lg*8;
                int si = e ^ SWZ(w);
                bh[nf] = *(const bf16x8*)(xh + si);
                bl[nf] = *(const bf16x8*)(xl + si);
            }
#pragma unroll
            for (int kf = 0; kf < 2; ++kf)
#pragma unroll
                for (int nf = 0; nf < 4; ++nf) {
                    acc[rr][kf][nf] = __builtin_amdgcn_mfma_f32_16x16x32_bf16(ah[kf], bh[nf], acc[rr][kf][nf], 0, 0, 0);
                    acc[rr][kf][nf] = __builtin_amdgcn_mfma_f32_16x16x32_bf16(al[kf], bh[nf], acc[rr][kf][nf], 0, 0, 0);
                    acc[rr][kf][nf] = __builtin_amdgcn_mfma_f32_16x16x32_bf16(ah[kf], bl[nf], acc[rr][kf][nf], 0, 0, 0);
                }
        }
    }

    // bias + store y + argmax (C/D: row=lg*4+r, col=l15 [m89])
#pragma unroll
    for (int rr = 0; rr < 2; ++rr)
#pragma unroll
    for (int nf = 0; nf < 4; ++nf) {
        int n = nf*16 + l15;
        float vm = -3.4e38f; int im = 0;
#pragma unroll
        for (int kf = 0; kf < 2; ++kf)
#pragma unroll
            for (int r = 0; r < 4; ++r) {
                int k = kbase + kf*16 + lg*4 + r;
                float v = acc[rr][kf][nf][r] + biasL[k];
                if (n < OHW) y[(((size_t)b*OC + k)*OHW + (oh0 + rr))*OHW + n] = v;
                if (v > vm) { vm = v; im = k; }        // ascending k, strict >
            }
        {
            float ov = __shfl_xor(vm, 16); int oi = __shfl_xor(im, 16);
            if (ov > vm || (ov == vm && oi < im)) { vm = ov; im = oi; }
            ov = __shfl_xor(vm, 32); oi = __shfl_xor(im, 32);
            if (ov > vm || (ov == vm && oi < im)) { vm = ov; im = oi; }
        }
        if (lg == 0) { redv[wv][rr][n] = vm; redi[wv][rr][n] = im; }
    }
    __syncthreads();
    if (tid < 128) {
        int rr = tid >> 6, n = tid & 63;
        if (n < OHW) {
            float bv = redv[0][rr][n]; int bi = redi[0][rr][n];
#pragma unroll
            for (int wvv = 1; wvv < 4; ++wvv) {
                float v = redv[wvv][rr][n]; int i2 = redi[wvv][rr][n];
                if (v > bv || (v == bv && i2 < bi)) { bv = v; bi = i2; }
            }
            winners[(size_t)b*LOCS + (oh0 + rr)*OHW + n] = bi;
        }
    }
}

// ---------------- K3: Hebbian via one-hot-mask MFMA, per-block partials ---
__global__ __launch_bounds__(512) void hebb_kernel(
    const float* __restrict__ x, const int* __restrict__ winners,
    float* __restrict__ part, int nblk)
{
    __shared__ short xR[IC*10*72];   // [c][row][72], bf16 hi; 92160 B
    __shared__ int winL[8*64];

    const int tid = threadIdx.x;
    const int lane = tid & 63, wv = tid >> 6;
    const int l15 = lane & 15, lg = lane >> 4;
    const int myk = wv*16 + l15;

    int off0[12];
#pragma unroll
    for (int nf = 0; nf < 12; ++nf) {
        int np = nf*16 + l15;        // 0..191 = c*3+i
        int c = np / 3, i = np % 3;
        off0[nf] = (c*10 + i)*72;
    }

    f32x4 acc[3][12];
#pragma unroll
    for (int j = 0; j < 3; ++j)
#pragma unroll
        for (int nf = 0; nf < 12; ++nf)
            acc[j][nf] = (f32x4){0.f,0.f,0.f,0.f};

    for (int t = blockIdx.x; t < 256; t += nblk) {
        const int b = t >> 3, tile = t & 7;
        const int oh0 = tile*8;
        const int NR = (tile == 7) ? 6 : 8;
        const int rows = NR + 2;

        __syncthreads();
        for (int it = tid; it < IC*rows*16; it += 512) {
            int wq = it & 15;
            int t2 = it >> 4;
            int r = t2 % rows, c = t2 / rows;
            const float* p = x + (((size_t)(b*IC + c))*64 + (oh0 + r))*64 + wq*4;
            float4 a = *(const float4*)p;
            unsigned u0 = (unsigned)f2bf(a.x) | ((unsigned)f2bf(a.y) << 16);
            unsigned u1 = (unsigned)f2bf(a.z) | ((unsigned)f2bf(a.w) << 16);
            int e = (c*10 + r)*72 + wq*4;
            ((unsigned*)xR)[(e >> 1)]     = u0;
            ((unsigned*)xR)[(e >> 1) + 1] = u1;
        }
        for (int tt = tid; tt < NR*64; tt += 512) {
            int r = tt >> 6, ow = tt & 63;
            winL[tt] = (ow < OHW) ? winners[(size_t)b*LOCS + (oh0 + r)*OHW + ow] : -1;
        }
        __syncthreads();

        for (int r = 0; r < NR; ++r) {
#pragma unroll
            for (int h = 0; h < 2; ++h) {
                const int base = h*32 + lg*8;
                const int* wrow = &winL[r*64];
                int wreg[8];
                *(int4*)&wreg[0] = *(const int4*)&wrow[base];
                *(int4*)&wreg[4] = *(const int4*)&wrow[base + 4];
                const int wm1 = (base >= 1) ? wrow[base-1] : -1;
                const int wm2 = (base >= 2) ? wrow[base-2] : -1;
                union U8 { unsigned u[4]; bf16x8 v; };
                bf16x8 am[3];
#pragma unroll
                for (int j = 0; j < 3; ++j) {
                    U8 tmp;
#pragma unroll
                    for (int p2 = 0; p2 < 4; ++p2) {
                        int t0 = p2*2, t1 = t0 + 1;
                        int s0 = (t0 >= j) ? wreg[t0-j] : ((j - t0 == 1) ? wm1 : wm2);
                        int s1 = (t1 >= j) ? wreg[t1-j] : ((j - t1 == 1) ? wm1 : wm2);
                        tmp.u[p2] = ((s0 == myk) ? 0x3F80u : 0u)
                                  | (((s1 == myk) ? 0x3F80u : 0u) << 16);
                    }
                    am[j] = tmp.v;
                }
#pragma unroll
                for (int nf = 0; nf < 12; ++nf) {
                    const bf16x8 bb = *(const bf16x8*)&xR[off0[nf] + r*72 + base];
#pragma unroll
                    for (int j = 0; j < 3; ++j)
                        acc[j][nf] = __builtin_amdgcn_mfma_f32_16x16x32_bf16(am[j], bb, acc[j][nf], 0, 0, 0);
                }
            }
        }
    }

    float* dst = part + (size_t)blockIdx.x*UPD_SIZE;
#pragma unroll
    for (int j = 0; j < 3; ++j)
#pragma unroll
        for (int nf = 0; nf < 12; ++nf) {
            int np = nf*16 + l15;
            int row = np*3 + j;                 // == c*9 + i*3 + j
            int k0  = wv*16 + lg*4;
            *(f32x4*)(dst + row*OC + k0) = acc[j][nf];
        }
}

// ---------------- K4: reduce partials (coalesced) + scale + transpose -----
__global__ __launch_bounds__(256) void final_kernel(const float* __restrict__ part,
                                                    float* __restrict__ upd, int nblk) {
    int t = blockIdx.x*256 + threadIdx.x;
    int idx = t*4;
    f32x4 s = (f32x4){0.f,0.f,0.f,0.f};
    for (int p = 0; p < nblk; ++p)
        s += *(const f32x4*)(part + (size_t)p*UPD_SIZE + idx);
    int row = idx >> 7;
    int k0  = idx & 127;
    const float inv = 1.0f / 123008.0f;
#pragma unroll
    for (int r = 0; r < 4; ++r)
        upd[(size_t)(k0 + r)*576 + row] = s[r] * inv;
}

extern "C" void kernel_launch(void* const* d_in, const int* in_sizes, int n_in,
                              void* d_out, int out_size, void* d_ws, size_t ws_size,
                              hipStream_t stream) {
    const float* x    = (const float*)d_in[0];
    const float* w    = (const float*)d_in[1];
    const float* bias = (const float*)d_in[2];
    float* out = (float*)d_out;
    float* y   = out;
    float* upd = out + Y_SIZE;

    // ws: wH 147456 | wL 147456 | winners 492032 | partials nblk*294912
    const size_t fixed = 147456 + 147456 + 492032;   // 786944
    short* wHs     = (short*)d_ws;
    short* wLs     = (short*)((char*)d_ws + 147456);
    int*   winners = (int*)((char*)d_ws + 294912);
    float* part    = (float*)((char*)d_ws + fixed);

    size_t avail = (ws_size > fixed) ? (ws_size - fixed) : 0;
    int nblk = (int)(avail / ((size_t)UPD_SIZE*4));
    if (nblk > 256) nblk = 256;
    if (nblk < 1)   nblk = 1;

    wnorm_kernel<<<OC, IC, 0, stream>>>(w, wHs, wLs);
    conv_kernel<<<dim3(31, BATCH), 256, 0, stream>>>(x, wHs, wLs, bias, y, winners);
    hebb_kernel<<<nblk, 512, 0, stream>>>(x, winners, part, nblk);
    final_kernel<<<UPD_SIZE/4/256, 256, 0, stream>>>(part, upd, nblk);
}